// Round 9
// baseline (428.482 us; speedup 1.0000x reference)
//
#include <hip/hip_runtime.h>

#define N 4096
#define CIN 64
#define NB 2

typedef unsigned short u16;
typedef short bf16x8 __attribute__((ext_vector_type(8)));
typedef float f32x4 __attribute__((ext_vector_type(4)));

// workspace layout (float offsets). OFF_V region holds bf16 (u16) V.
// OFF_QK holds qkj[n][8] = q[n] . kj ; OFF_KJ holds 16 per-b kj partials (8x8)
#define OFF_QT 0
#define OFF_KT (OFF_QT + NB*N*8)
#define OFF_JT (OFF_KT + NB*N*8)
#define OFF_V  (OFF_JT + NB*N*8)
#define OFF_QK (OFF_V + NB*CIN*N)
#define OFF_MX (OFF_QK + NB*N*8)
#define OFF_SC (OFF_MX + NB*N)
#define OFF_KJ (OFF_SC + NB*N)     // NB*16*64 floats of kj partials

__device__ __forceinline__ u16 f2bf(float f) {
    union { float f; unsigned u; } v; v.f = f;
    unsigned r = (v.u + 0x7fffu + ((v.u >> 16) & 1u)) >> 16;  // RNE
    return (u16)r;
}

// ---- prep v2: grid (16, 9, 2) block 512 ------------------------------------
// y<8  : V conv blocks (co0 = y*8), c-split halves (r5-verified body).
// y==8 : QKJ blocks — ALL 8 cq per block (8x less x traffic; prep was
//        L2-BW-bound: 117MB of x re-reads, r6 counters) + kj partial emit.
__global__ __launch_bounds__(512, 4) void prep(
        const float* __restrict__ x,
        const float* __restrict__ wq, const float* __restrict__ bq,
        const float* __restrict__ wk, const float* __restrict__ bk,
        const float* __restrict__ wj, const float* __restrict__ bj,
        const float* __restrict__ wv, const float* __restrict__ bv,
        float* __restrict__ ws, u16* __restrict__ vbf, float* __restrict__ out) {
    __shared__ union {
        float qkj[3][8][256];      // QKJ half-combine (24 KB)
        float accv[256][8];        // V half-combine
    } sh;
    __shared__ float kjpart[4][64];
    const int t    = threadIdx.x;
    const int tn   = t & 255;
    const int half = t >> 8;               // c-half: 0 -> c 0..31, 1 -> c 32..63
    const int y    = blockIdx.y;
    const int bx   = blockIdx.x;
    const int b    = blockIdx.z;
    const int n    = bx * 256 + tn;
    const float* xb = x + (size_t)b * CIN * N + n;
    const int c0base = half * 32;

    if (y == 8) {
        // ---------------- QKJ: all 8 cq, shared stencil loads ----------------
        const int lane = t & 63, wid = t >> 6;
        int d = n & 15, w = (n >> 4) & 15, h = n >> 8;
        int owl = (w > 0) ? -16 : 0,  owh = (w < 15) ? 16 : 0;
        int ohl = (h > 0) ? -256 : 0, ohh = (h < 15) ? 256 : 0;
        int odl = (d > 0) ? -1 : 0,   odh = (d < 15) ? 1 : 0;
        float mwl = (w > 0) ? 1.f : 0.f, mwh = (w < 15) ? 1.f : 0.f;
        float mhl = (h > 0) ? 1.f : 0.f, mhh = (h < 15) ? 1.f : 0.f;
        float mdl = (d > 0) ? 1.f : 0.f, mdh = (d < 15) ? 1.f : 0.f;
        float q[8], k[8], j[8];
#pragma unroll
        for (int cq = 0; cq < 8; ++cq) {
            q[cq] = half ? 0.f : bq[cq];
            k[cq] = half ? 0.f : bk[cq];
            j[cq] = half ? 0.f : bj[cq];
        }
        for (int c0i = 0; c0i < 32; c0i += 8) {
            const int c0 = c0base + c0i;
            float xc[8], xwl[8], xwh[8], xhl[8], xhh[8], xdl[8], xdh[8];
#pragma unroll
            for (int u = 0; u < 8; ++u) {       // 56 independent loads in flight
                const float* p = xb + (size_t)(c0 + u) * N;
                xc[u]  = p[0];
                xwl[u] = p[owl]; xwh[u] = p[owh];
                xhl[u] = p[ohl]; xhh[u] = p[ohh];
                xdl[u] = p[odl]; xdh[u] = p[odh];
            }
#pragma unroll
            for (int u = 0; u < 8; ++u) {
                int c = c0 + u;
                float xwlm = xwl[u] * mwl, xwhm = xwh[u] * mwh;
                float xhlm = xhl[u] * mhl, xhhm = xhh[u] * mhh;
                float xdlm = xdl[u] * mdl, xdhm = xdh[u] * mdh;
                float xcc  = xc[u];
#pragma unroll
                for (int cq = 0; cq < 8; ++cq) {
                    const float* wqr = wq + (cq * CIN + c) * 3;
                    const float* wkr = wk + (cq * CIN + c) * 3;
                    const float* wjr = wj + (cq * CIN + c) * 3;
                    q[cq] += wqr[0] * xwlm + wqr[1] * xcc + wqr[2] * xwhm;
                    k[cq] += wkr[0] * xhlm + wkr[1] * xcc + wkr[2] * xhhm;
                    j[cq] += wjr[0] * xdlm + wjr[1] * xcc + wjr[2] * xdhm;
                }
            }
        }
        if (half) {
#pragma unroll
            for (int cq = 0; cq < 8; ++cq) {
                sh.qkj[0][cq][tn] = q[cq];
                sh.qkj[1][cq][tn] = k[cq];
                sh.qkj[2][cq][tn] = j[cq];
            }
        }
        __syncthreads();
        if (!half) {
#pragma unroll
            for (int cq = 0; cq < 8; ++cq) {
                q[cq] += sh.qkj[0][cq][tn];
                k[cq] += sh.qkj[1][cq][tn];
                j[cq] += sh.qkj[2][cq][tn];
            }
            size_t base = (size_t)(b * N + n) * 8;
#pragma unroll
            for (int cq = 0; cq < 8; ++cq) {
                ws[OFF_QT + base + cq] = q[cq];
                ws[OFF_KT + base + cq] = k[cq];
                ws[OFF_JT + base + cq] = j[cq];
            }
            // kj partial: outer product reduce, 16 accs at a time (VGPR cap)
#pragma unroll
            for (int g = 0; g < 4; ++g) {
                float a16[16];
#pragma unroll
                for (int cc = 0; cc < 2; ++cc)
#pragma unroll
                    for (int dd = 0; dd < 8; ++dd)
                        a16[cc * 8 + dd] = k[g * 2 + cc] * j[dd];
#pragma unroll
                for (int s = 32; s >= 1; s >>= 1)
#pragma unroll
                    for (int i = 0; i < 16; ++i) a16[i] += __shfl_down(a16[i], s, 64);
                if (lane == 0) {
#pragma unroll
                    for (int i = 0; i < 16; ++i) kjpart[wid][g * 16 + i] = a16[i];
                }
            }
        }
        __syncthreads();
        if (t < 64) {
            float s = kjpart[0][t] + kjpart[1][t] + kjpart[2][t] + kjpart[3][t];
            ws[OFF_KJ + (size_t)(b * 16 + bx) * 64 + t] = s;
        }
    } else {
        // ---------------- V conv + out=x copy (r5-verified) ------------------
        int yy = y;
        int co0 = yy * 8;
        float acc[8];
#pragma unroll
        for (int i = 0; i < 8; ++i) acc[i] = half ? 0.f : bv[co0 + i];
        for (int c0i = 0; c0i < 32; c0i += 8) {
            const int c0 = c0base + c0i;
            float xv[8];
#pragma unroll
            for (int u = 0; u < 8; ++u) xv[u] = xb[(size_t)(c0 + u) * N];
#pragma unroll
            for (int u = 0; u < 8; ++u)
#pragma unroll
                for (int i = 0; i < 8; ++i)
                    acc[i] += wv[(co0 + i) * CIN + c0 + u] * xv[u];
            if ((c0 >> 3) == yy) {               // owning half copies out = x
#pragma unroll
                for (int u = 0; u < 8; ++u)
                    out[(size_t)(b * CIN + c0 + u) * N + n] = xv[u];
            }
        }
        if (half) {
#pragma unroll
            for (int i = 0; i < 8; ++i) sh.accv[tn][i] = acc[i];
        }
        __syncthreads();
        if (!half) {
#pragma unroll
            for (int i = 0; i < 8; ++i)
                vbf[(size_t)(b * CIN + co0 + i) * N + n] = f2bf(acc[i] + sh.accv[tn][i]);
        }
    }
}

// ---- pass1 v2: kj from partials + qkj + two-phase softmax stats ------------
// grid 2048, block 512. Absorbs old kjqkj kernel (launch boundary ~15us).
__global__ __launch_bounds__(512, 4) void pass1(const float* __restrict__ ws_in,
                                                float* __restrict__ ws,
                                                const float* __restrict__ gamma) {
    __shared__ float kjs[64];
    __shared__ float smx[8][4];     // [m-eighth wave][row]
    __shared__ float ssum[8][4];
    const int t = threadIdx.x, lane = t & 63, wid = t >> 6;
    const int r0 = blockIdx.x * 4;  // global row base (b*N+n)
    const int b  = r0 >> 12;
    const float* ktb = ws_in + OFF_KT + (size_t)b * N * 8;

    // kj = sum of 16 per-bx partials (4KB, L2-hot)
    if (t < 64) {
        const float* kjw = ws_in + OFF_KJ + (size_t)b * 16 * 64;
        float s = 0.f;
#pragma unroll
        for (int p = 0; p < 16; ++p) s += kjw[p * 64 + t];
        kjs[t] = s;
    }
    __syncthreads();

    // qkj for this block's 4 rows (every thread; kj read from LDS broadcast)
    float4 qa[4], qb[4];
#pragma unroll
    for (int rr = 0; rr < 4; ++rr) {
        const float4* q4 = (const float4*)(ws_in + OFF_QT + (size_t)(r0 + rr) * 8);
        float4 a4 = q4[0], b4 = q4[1];
        float qv[8] = {a4.x, a4.y, a4.z, a4.w, b4.x, b4.y, b4.z, b4.w};
        float o[8];
#pragma unroll
        for (int dd = 0; dd < 8; ++dd) {
            float a = 0.f;
#pragma unroll
            for (int c = 0; c < 8; ++c) a += qv[c] * kjs[c * 8 + dd];
            o[dd] = a;
        }
        qa[rr] = make_float4(o[0], o[1], o[2], o[3]);
        qb[rr] = make_float4(o[4], o[5], o[6], o[7]);
    }
    // publish qkj rows for pass2 (wave 0, lanes 0..31; runtime rr via reload)
    if (wid == 0 && lane < 32) {
        const int rr = lane >> 3, dd = lane & 7;
        const float* qr = ws_in + OFF_QT + (size_t)(r0 + rr) * 8;
        float o = 0.f;
#pragma unroll
        for (int c = 0; c < 8; ++c) o += qr[c] * kjs[c * 8 + dd];
        ws[OFF_QK + (size_t)r0 * 8 + lane] = o;   // == (r0+rr)*8 + dd
    }

    float as[4][8];                 // scores in registers (32 VGPRs, no spill)
#pragma unroll
    for (int i = 0; i < 8; ++i) {
        const int m = wid * 512 + i * 64 + lane;
        const float4* kk4 = (const float4*)(ktb + (size_t)m * 8);
        float4 ka = kk4[0], kb2 = kk4[1];
#pragma unroll
        for (int rr = 0; rr < 4; ++rr)
            as[rr][i] = qa[rr].x * ka.x + qa[rr].y * ka.y + qa[rr].z * ka.z + qa[rr].w * ka.w
                      + qb[rr].x * kb2.x + qb[rr].y * kb2.y + qb[rr].z * kb2.z + qb[rr].w * kb2.w;
    }

    float mx[4];
#pragma unroll
    for (int rr = 0; rr < 4; ++rr) {
        float m01 = fmaxf(fmaxf(as[rr][0], as[rr][1]), fmaxf(as[rr][2], as[rr][3]));
        float m23 = fmaxf(fmaxf(as[rr][4], as[rr][5]), fmaxf(as[rr][6], as[rr][7]));
        mx[rr] = fmaxf(m01, m23);
    }
#pragma unroll
    for (int s = 32; s >= 1; s >>= 1)
#pragma unroll
        for (int rr = 0; rr < 4; ++rr)
            mx[rr] = fmaxf(mx[rr], __shfl_xor(mx[rr], s, 64));
    if (lane == 0) {
#pragma unroll
        for (int rr = 0; rr < 4; ++rr) smx[wid][rr] = mx[rr];
    }
    __syncthreads();
    float gm[4];
#pragma unroll
    for (int rr = 0; rr < 4; ++rr) {
        float g0 = fmaxf(fmaxf(smx[0][rr], smx[1][rr]), fmaxf(smx[2][rr], smx[3][rr]));
        float g1 = fmaxf(fmaxf(smx[4][rr], smx[5][rr]), fmaxf(smx[6][rr], smx[7][rr]));
        gm[rr] = fmaxf(g0, g1);
    }

    float sm[4];
#pragma unroll
    for (int rr = 0; rr < 4; ++rr) {
        float s0 = __expf(as[rr][0] - gm[rr]) + __expf(as[rr][1] - gm[rr])
                 + __expf(as[rr][2] - gm[rr]) + __expf(as[rr][3] - gm[rr]);
        float s1 = __expf(as[rr][4] - gm[rr]) + __expf(as[rr][5] - gm[rr])
                 + __expf(as[rr][6] - gm[rr]) + __expf(as[rr][7] - gm[rr]);
        sm[rr] = s0 + s1;
    }
#pragma unroll
    for (int s = 32; s >= 1; s >>= 1)
#pragma unroll
        for (int rr = 0; rr < 4; ++rr)
            sm[rr] += __shfl_xor(sm[rr], s, 64);
    if (lane == 0) {
#pragma unroll
        for (int rr = 0; rr < 4; ++rr) ssum[wid][rr] = sm[rr];
    }
    __syncthreads();
    if (t < 4) {
        float g0 = fmaxf(fmaxf(smx[0][t], smx[1][t]), fmaxf(smx[2][t], smx[3][t]));
        float g1 = fmaxf(fmaxf(smx[4][t], smx[5][t]), fmaxf(smx[6][t], smx[7][t]));
        float g  = fmaxf(g0, g1);
        float tt = ((ssum[0][t] + ssum[1][t]) + (ssum[2][t] + ssum[3][t]))
                 + ((ssum[4][t] + ssum[5][t]) + (ssum[6][t] + ssum[7][t]));
        ws[OFF_MX + r0 + t] = g;
        ws[OFF_SC + r0 + t] = gamma[0] / tt;
    }
}

// ---- pass2: V_bf16 . P'_bf16 via MFMA; LDS stride 72->68 (2-way banks) -----
// 72 u16 = 36 dw -> MFMA frag reads hit banks 4*(l16+lq)%32 = 8-way conflict
// (3.93M SQ_LDS_BANK_CONFLICT, r8). 68 u16 = 34 dw -> 2*l16+4*lq: 2/bank=free.
#define P2S 68
__global__ __launch_bounds__(256) void pass2(const float* __restrict__ ws,
                                             const u16* __restrict__ vbf,
                                             float* __restrict__ out) {
    __shared__ u16 Pt[64][P2S];     // P' tile: [m][n]  (B-frag: B[k=n][col=m])
    __shared__ u16 Vt[64][P2S];     // V tile:  [c][n]  (A-frag: A[row=c][k=n])
    __shared__ float ks[64][8];     // k for this m-tile
    const int t  = threadIdx.x;
    const int b  = blockIdx.z;
    const int m0 = blockIdx.x * 64;
    const int ns = blockIdx.y;
    const float* qkT = ws + OFF_QK + (size_t)b * N * 8;
    const float* ktb = ws + OFF_KT + (size_t)b * N * 8;
    const float* mxv = ws + OFF_MX + (size_t)b * N;
    const float* scv = ws + OFF_SC + (size_t)b * N;
    const u16*   vb  = vbf + (size_t)b * CIN * N;

    if (t < 128) ((float4*)ks)[t] = ((const float4*)(ktb + (size_t)m0 * 8))[t];

    const int lane = t & 63;
    const int wid  = t >> 6;        // wave id -> m-subtile
    const int l16  = lane & 15;
    const int lq   = lane >> 4;     // lane quad -> k-octet / acc row group
    const int vc   = t >> 3;        // V staging row 0..31
    const int vseg = t & 7;

    f32x4 acc[4];
#pragma unroll
    for (int i = 0; i < 4; ++i) acc[i] = (f32x4){0.f, 0.f, 0.f, 0.f};

    for (int ch = 0; ch < 8; ++ch) {
        const int n0 = ns * 512 + ch * 64;
        const int n  = n0 + lane;
        const float4* q4 = (const float4*)(qkT + (size_t)n * 8);
        float4 qa = q4[0], qb = q4[1];
        float mxl = mxv[n], sl = scv[n];
        uint4 v0 = *(const uint4*)(vb + (size_t)vc        * N + n0 + vseg * 8);
        uint4 v1 = *(const uint4*)(vb + (size_t)(vc + 32) * N + n0 + vseg * 8);
        __syncthreads();            // prev chunk's MFMA reads done (chunk 0: ks staged)
#pragma unroll
        for (int r = 0; r < 16; ++r) {
            int mi = wid * 16 + r;
            float4 k0 = *(const float4*)&ks[mi][0];
            float4 k1 = *(const float4*)&ks[mi][4];
            float a = qa.x * k0.x + qa.y * k0.y + qa.z * k0.z + qa.w * k0.w
                    + qb.x * k1.x + qb.y * k1.y + qb.z * k1.z + qb.w * k1.w;
            Pt[mi][lane] = f2bf(__expf(a - mxl) * sl);  // gamma/rowsum folded in
        }
        *(uint4*)&Vt[vc][vseg * 8]      = v0;
        *(uint4*)&Vt[vc + 32][vseg * 8] = v1;
        __syncthreads();
#pragma unroll
        for (int kk = 0; kk < 2; ++kk) {
            int k0i = kk * 32 + lq * 8;
            bf16x8 bfrag = *(const bf16x8*)&Pt[wid * 16 + l16][k0i];
#pragma unroll
            for (int ct = 0; ct < 4; ++ct) {
                bf16x8 afrag = *(const bf16x8*)&Vt[ct * 16 + l16][k0i];
                acc[ct] = __builtin_amdgcn_mfma_f32_16x16x32_bf16(afrag, bfrag, acc[ct], 0, 0, 0);
            }
        }
    }
    float* ob = out + (size_t)b * CIN * N;
    const int mcol = m0 + wid * 16 + l16;
#pragma unroll
    for (int ct = 0; ct < 4; ++ct)
#pragma unroll
        for (int r = 0; r < 4; ++r) {
            int c = ct * 16 + lq * 4 + r;
            atomicAdd(&ob[(size_t)c * N + mcol], acc[ct][r]);
        }
}

extern "C" void kernel_launch(void* const* d_in, const int* in_sizes, int n_in,
                              void* d_out, int out_size, void* d_ws, size_t ws_size,
                              hipStream_t stream) {
    const float* x  = (const float*)d_in[0];
    const float* wq = (const float*)d_in[1];
    const float* bq = (const float*)d_in[2];
    const float* wk = (const float*)d_in[3];
    const float* bk = (const float*)d_in[4];
    const float* wj = (const float*)d_in[5];
    const float* bj = (const float*)d_in[6];
    const float* wv = (const float*)d_in[7];
    const float* bv = (const float*)d_in[8];
    const float* gamma = (const float*)d_in[9];
    float* ws  = (float*)d_ws;
    float* out = (float*)d_out;
    u16* vbf = (u16*)(ws + OFF_V);

    // 3 launches (kjqkj absorbed into prep+pass1; each boundary ~15us)
    prep<<<dim3(16, 9, 2), 512, 0, stream>>>(x, wq, bq, wk, bk, wj, bj, wv, bv, ws, vbf, out);
    pass1<<<2048, 512, 0, stream>>>(ws, ws, gamma);
    pass2<<<dim3(64, 8, 2), 256, 0, stream>>>(ws, vbf, out);
}

// Round 10
// 160.196 us; speedup vs baseline: 2.6747x; 2.6747x over previous
//
#include <hip/hip_runtime.h>

#define N 4096
#define CIN 64
#define NB 2

typedef unsigned short u16;
typedef short bf16x8 __attribute__((ext_vector_type(8)));
typedef float f32x4 __attribute__((ext_vector_type(4)));

// workspace layout (float offsets). OFF_V region holds bf16 (u16) V.
// OFF_QK holds qkj[n][8] = q[n] . kj ; OFF_KJ holds 16 per-b kj partials (8x8)
#define OFF_QT 0
#define OFF_KT (OFF_QT + NB*N*8)
#define OFF_JT (OFF_KT + NB*N*8)
#define OFF_V  (OFF_JT + NB*N*8)
#define OFF_QK (OFF_V + NB*CIN*N)
#define OFF_MX (OFF_QK + NB*N*8)
#define OFF_SC (OFF_MX + NB*N)
#define OFF_KJ (OFF_SC + NB*N)     // NB*16*64 floats of kj partials

__device__ __forceinline__ u16 f2bf(float f) {
    union { float f; unsigned u; } v; v.f = f;
    unsigned r = (v.u + 0x7fffu + ((v.u >> 16) & 1u)) >> 16;  // RNE
    return (u16)r;
}

// ---- prep v3: grid (16, 10, 2) block 512 -----------------------------------
// y<8 : V conv blocks (r5-verified body).
// y=8 : type A — k & j convs for ALL 8 cq (16 accs, 5-pt stencil, quartets)
//       + kj partial emit. y=9 : type B — q convs for all 8 cq (8 accs, 3-pt).
// Split exists because r9's single 8-cq branch (24 accs + 56 temps) spilled
// ~7KB/thread (WRITE_SIZE 109MB, occupancy 0.06%).
__global__ __launch_bounds__(512, 4) void prep(
        const float* __restrict__ x,
        const float* __restrict__ wq, const float* __restrict__ bq,
        const float* __restrict__ wk, const float* __restrict__ bk,
        const float* __restrict__ wj, const float* __restrict__ bj,
        const float* __restrict__ wv, const float* __restrict__ bv,
        float* __restrict__ ws, u16* __restrict__ vbf, float* __restrict__ out) {
    __shared__ union {
        float kj2[2][8][256];      // type A half-combine (16 KB)
        float q1[8][256];          // type B half-combine (8 KB)
        float accv[256][8];        // V half-combine (8 KB)
    } sh;
    __shared__ float kjpart[4][64];
    const int t    = threadIdx.x;
    const int tn   = t & 255;
    const int half = t >> 8;               // c-half: 0 -> c 0..31, 1 -> c 32..63
    const int y    = blockIdx.y;
    const int bx   = blockIdx.x;
    const int b    = blockIdx.z;
    const int n    = bx * 256 + tn;
    const float* xb = x + (size_t)b * CIN * N + n;
    const int c0base = half * 32;

    if (y == 8) {
        // -------- type A: k (h-stencil) + j (d-stencil), all 8 cq -----------
        const int lane = t & 63, wid = t >> 6;
        int d = n & 15, h = n >> 8;
        int ohl = (h > 0) ? -256 : 0, ohh = (h < 15) ? 256 : 0;
        int odl = (d > 0) ? -1 : 0,   odh = (d < 15) ? 1 : 0;
        float mhl = (h > 0) ? 1.f : 0.f, mhh = (h < 15) ? 1.f : 0.f;
        float mdl = (d > 0) ? 1.f : 0.f, mdh = (d < 15) ? 1.f : 0.f;
        float k[8], j[8];
#pragma unroll
        for (int cq = 0; cq < 8; ++cq) {
            k[cq] = half ? 0.f : bk[cq];
            j[cq] = half ? 0.f : bj[cq];
        }
        for (int c0i = 0; c0i < 32; c0i += 4) {   // channel quartets: 20 temps
            const int c0 = c0base + c0i;
            float xc[4], xhl[4], xhh[4], xdl[4], xdh[4];
#pragma unroll
            for (int u = 0; u < 4; ++u) {
                const float* p = xb + (size_t)(c0 + u) * N;
                xc[u]  = p[0];
                xhl[u] = p[ohl]; xhh[u] = p[ohh];
                xdl[u] = p[odl]; xdh[u] = p[odh];
            }
#pragma unroll
            for (int u = 0; u < 4; ++u) {
                xhl[u] *= mhl; xhh[u] *= mhh;
                xdl[u] *= mdl; xdh[u] *= mdh;
            }
#pragma unroll
            for (int cq = 0; cq < 8; ++cq) {       // 12 consecutive floats/row
                const float4* wk4 = (const float4*)(wk + (cq * CIN + c0) * 3);
                float4 ka4 = wk4[0], kb4 = wk4[1], kc4 = wk4[2];
                k[cq] += ka4.x * xhl[0] + ka4.y * xc[0] + ka4.z * xhh[0]
                       + ka4.w * xhl[1] + kb4.x * xc[1] + kb4.y * xhh[1]
                       + kb4.z * xhl[2] + kb4.w * xc[2] + kc4.x * xhh[2]
                       + kc4.y * xhl[3] + kc4.z * xc[3] + kc4.w * xhh[3];
                const float4* wj4 = (const float4*)(wj + (cq * CIN + c0) * 3);
                float4 ja4 = wj4[0], jb4 = wj4[1], jc4 = wj4[2];
                j[cq] += ja4.x * xdl[0] + ja4.y * xc[0] + ja4.z * xdh[0]
                       + ja4.w * xdl[1] + jb4.x * xc[1] + jb4.y * xdh[1]
                       + jb4.z * xdl[2] + jb4.w * xc[2] + jc4.x * xdh[2]
                       + jc4.y * xdl[3] + jc4.z * xc[3] + jc4.w * xdh[3];
            }
        }
        if (half) {
#pragma unroll
            for (int cq = 0; cq < 8; ++cq) {
                sh.kj2[0][cq][tn] = k[cq];
                sh.kj2[1][cq][tn] = j[cq];
            }
        }
        __syncthreads();
        if (!half) {
#pragma unroll
            for (int cq = 0; cq < 8; ++cq) {
                k[cq] += sh.kj2[0][cq][tn];
                j[cq] += sh.kj2[1][cq][tn];
            }
            size_t base = (size_t)(b * N + n) * 8;
#pragma unroll
            for (int cq = 0; cq < 8; ++cq) {
                ws[OFF_KT + base + cq] = k[cq];
                ws[OFF_JT + base + cq] = j[cq];
            }
            // kj partials (r9-verified): 4 groups of 16 accs, shuffle reduce
#pragma unroll
            for (int g = 0; g < 4; ++g) {
                float a16[16];
#pragma unroll
                for (int cc = 0; cc < 2; ++cc)
#pragma unroll
                    for (int dd = 0; dd < 8; ++dd)
                        a16[cc * 8 + dd] = k[g * 2 + cc] * j[dd];
#pragma unroll
                for (int s = 32; s >= 1; s >>= 1)
#pragma unroll
                    for (int i = 0; i < 16; ++i) a16[i] += __shfl_down(a16[i], s, 64);
                if (lane == 0) {
#pragma unroll
                    for (int i = 0; i < 16; ++i) kjpart[wid][g * 16 + i] = a16[i];
                }
            }
        }
        __syncthreads();
        if (t < 64) {
            float s = kjpart[0][t] + kjpart[1][t] + kjpart[2][t] + kjpart[3][t];
            ws[OFF_KJ + (size_t)(b * 16 + bx) * 64 + t] = s;
        }
    } else if (y == 9) {
        // -------- type B: q (w-stencil), all 8 cq ---------------------------
        int w = (n >> 4) & 15;
        int owl = (w > 0) ? -16 : 0, owh = (w < 15) ? 16 : 0;
        float mwl = (w > 0) ? 1.f : 0.f, mwh = (w < 15) ? 1.f : 0.f;
        float q[8];
#pragma unroll
        for (int cq = 0; cq < 8; ++cq) q[cq] = half ? 0.f : bq[cq];
        for (int c0i = 0; c0i < 32; c0i += 8) {   // octets: 24 temps
            const int c0 = c0base + c0i;
            float xc[8], xwl[8], xwh[8];
#pragma unroll
            for (int u = 0; u < 8; ++u) {
                const float* p = xb + (size_t)(c0 + u) * N;
                xc[u] = p[0]; xwl[u] = p[owl]; xwh[u] = p[owh];
            }
#pragma unroll
            for (int u = 0; u < 8; ++u) { xwl[u] *= mwl; xwh[u] *= mwh; }
#pragma unroll
            for (int cq = 0; cq < 8; ++cq) {       // 24 consecutive floats/row
                const float4* w4 = (const float4*)(wq + (cq * CIN + c0) * 3);
                float4 a4 = w4[0], b4 = w4[1], c4 = w4[2],
                       d4 = w4[3], e4 = w4[4], f4 = w4[5];
                q[cq] += a4.x * xwl[0] + a4.y * xc[0] + a4.z * xwh[0]
                       + a4.w * xwl[1] + b4.x * xc[1] + b4.y * xwh[1]
                       + b4.z * xwl[2] + b4.w * xc[2] + c4.x * xwh[2]
                       + c4.y * xwl[3] + c4.z * xc[3] + c4.w * xwh[3]
                       + d4.x * xwl[4] + d4.y * xc[4] + d4.z * xwh[4]
                       + d4.w * xwl[5] + e4.x * xc[5] + e4.y * xwh[5]
                       + e4.z * xwl[6] + e4.w * xc[6] + f4.x * xwh[6]
                       + f4.y * xwl[7] + f4.z * xc[7] + f4.w * xwh[7];
            }
        }
        if (half) {
#pragma unroll
            for (int cq = 0; cq < 8; ++cq) sh.q1[cq][tn] = q[cq];
        }
        __syncthreads();
        if (!half) {
            size_t base = (size_t)(b * N + n) * 8;
#pragma unroll
            for (int cq = 0; cq < 8; ++cq)
                ws[OFF_QT + base + cq] = q[cq] + sh.q1[cq][tn];
        }
    } else {
        // -------- V conv + out=x copy (r5-verified) -------------------------
        int yy = y;
        int co0 = yy * 8;
        float acc[8];
#pragma unroll
        for (int i = 0; i < 8; ++i) acc[i] = half ? 0.f : bv[co0 + i];
        for (int c0i = 0; c0i < 32; c0i += 8) {
            const int c0 = c0base + c0i;
            float xv[8];
#pragma unroll
            for (int u = 0; u < 8; ++u) xv[u] = xb[(size_t)(c0 + u) * N];
#pragma unroll
            for (int u = 0; u < 8; ++u)
#pragma unroll
                for (int i = 0; i < 8; ++i)
                    acc[i] += wv[(co0 + i) * CIN + c0 + u] * xv[u];
            if ((c0 >> 3) == yy) {               // owning half copies out = x
#pragma unroll
                for (int u = 0; u < 8; ++u)
                    out[(size_t)(b * CIN + c0 + u) * N + n] = xv[u];
            }
        }
        if (half) {
#pragma unroll
            for (int i = 0; i < 8; ++i) sh.accv[tn][i] = acc[i];
        }
        __syncthreads();
        if (!half) {
#pragma unroll
            for (int i = 0; i < 8; ++i)
                vbf[(size_t)(b * CIN + co0 + i) * N + n] = f2bf(acc[i] + sh.accv[tn][i]);
        }
    }
}

// ---- pass1: kj from partials + qkj + two-phase softmax stats (r9 verified) -
__global__ __launch_bounds__(512, 4) void pass1(const float* __restrict__ ws_in,
                                                float* __restrict__ ws,
                                                const float* __restrict__ gamma) {
    __shared__ float kjs[64];
    __shared__ float smx[8][4];     // [m-eighth wave][row]
    __shared__ float ssum[8][4];
    const int t = threadIdx.x, lane = t & 63, wid = t >> 6;
    const int r0 = blockIdx.x * 4;  // global row base (b*N+n)
    const int b  = r0 >> 12;
    const float* ktb = ws_in + OFF_KT + (size_t)b * N * 8;

    // kj = sum of 16 per-bx partials (4KB, L2-hot)
    if (t < 64) {
        const float* kjw = ws_in + OFF_KJ + (size_t)b * 16 * 64;
        float s = 0.f;
#pragma unroll
        for (int p = 0; p < 16; ++p) s += kjw[p * 64 + t];
        kjs[t] = s;
    }
    __syncthreads();

    // qkj for this block's 4 rows (every thread; kj read from LDS broadcast)
    float4 qa[4], qb[4];
#pragma unroll
    for (int rr = 0; rr < 4; ++rr) {
        const float4* q4 = (const float4*)(ws_in + OFF_QT + (size_t)(r0 + rr) * 8);
        float4 a4 = q4[0], b4 = q4[1];
        float qv[8] = {a4.x, a4.y, a4.z, a4.w, b4.x, b4.y, b4.z, b4.w};
        float o[8];
#pragma unroll
        for (int dd = 0; dd < 8; ++dd) {
            float a = 0.f;
#pragma unroll
            for (int c = 0; c < 8; ++c) a += qv[c] * kjs[c * 8 + dd];
            o[dd] = a;
        }
        qa[rr] = make_float4(o[0], o[1], o[2], o[3]);
        qb[rr] = make_float4(o[4], o[5], o[6], o[7]);
    }
    // publish qkj rows for pass2 (wave 0, lanes 0..31)
    if (wid == 0 && lane < 32) {
        const int rr = lane >> 3, dd = lane & 7;
        const float* qr = ws_in + OFF_QT + (size_t)(r0 + rr) * 8;
        float o = 0.f;
#pragma unroll
        for (int c = 0; c < 8; ++c) o += qr[c] * kjs[c * 8 + dd];
        ws[OFF_QK + (size_t)r0 * 8 + lane] = o;   // == (r0+rr)*8 + dd
    }

    float as[4][8];                 // scores in registers (32 VGPRs, no spill)
#pragma unroll
    for (int i = 0; i < 8; ++i) {
        const int m = wid * 512 + i * 64 + lane;
        const float4* kk4 = (const float4*)(ktb + (size_t)m * 8);
        float4 ka = kk4[0], kb2 = kk4[1];
#pragma unroll
        for (int rr = 0; rr < 4; ++rr)
            as[rr][i] = qa[rr].x * ka.x + qa[rr].y * ka.y + qa[rr].z * ka.z + qa[rr].w * ka.w
                      + qb[rr].x * kb2.x + qb[rr].y * kb2.y + qb[rr].z * kb2.z + qb[rr].w * kb2.w;
    }

    float mx[4];
#pragma unroll
    for (int rr = 0; rr < 4; ++rr) {
        float m01 = fmaxf(fmaxf(as[rr][0], as[rr][1]), fmaxf(as[rr][2], as[rr][3]));
        float m23 = fmaxf(fmaxf(as[rr][4], as[rr][5]), fmaxf(as[rr][6], as[rr][7]));
        mx[rr] = fmaxf(m01, m23);
    }
#pragma unroll
    for (int s = 32; s >= 1; s >>= 1)
#pragma unroll
        for (int rr = 0; rr < 4; ++rr)
            mx[rr] = fmaxf(mx[rr], __shfl_xor(mx[rr], s, 64));
    if (lane == 0) {
#pragma unroll
        for (int rr = 0; rr < 4; ++rr) smx[wid][rr] = mx[rr];
    }
    __syncthreads();
    float gm[4];
#pragma unroll
    for (int rr = 0; rr < 4; ++rr) {
        float g0 = fmaxf(fmaxf(smx[0][rr], smx[1][rr]), fmaxf(smx[2][rr], smx[3][rr]));
        float g1 = fmaxf(fmaxf(smx[4][rr], smx[5][rr]), fmaxf(smx[6][rr], smx[7][rr]));
        gm[rr] = fmaxf(g0, g1);
    }

    float sm[4];
#pragma unroll
    for (int rr = 0; rr < 4; ++rr) {
        float s0 = __expf(as[rr][0] - gm[rr]) + __expf(as[rr][1] - gm[rr])
                 + __expf(as[rr][2] - gm[rr]) + __expf(as[rr][3] - gm[rr]);
        float s1 = __expf(as[rr][4] - gm[rr]) + __expf(as[rr][5] - gm[rr])
                 + __expf(as[rr][6] - gm[rr]) + __expf(as[rr][7] - gm[rr]);
        sm[rr] = s0 + s1;
    }
#pragma unroll
    for (int s = 32; s >= 1; s >>= 1)
#pragma unroll
        for (int rr = 0; rr < 4; ++rr)
            sm[rr] += __shfl_xor(sm[rr], s, 64);
    if (lane == 0) {
#pragma unroll
        for (int rr = 0; rr < 4; ++rr) ssum[wid][rr] = sm[rr];
    }
    __syncthreads();
    if (t < 4) {
        float g0 = fmaxf(fmaxf(smx[0][t], smx[1][t]), fmaxf(smx[2][t], smx[3][t]));
        float g1 = fmaxf(fmaxf(smx[4][t], smx[5][t]), fmaxf(smx[6][t], smx[7][t]));
        float g  = fmaxf(g0, g1);
        float tt = ((ssum[0][t] + ssum[1][t]) + (ssum[2][t] + ssum[3][t]))
                 + ((ssum[4][t] + ssum[5][t]) + (ssum[6][t] + ssum[7][t]));
        ws[OFF_MX + r0 + t] = g;
        ws[OFF_SC + r0 + t] = gamma[0] / tt;
    }
}

// ---- pass2: out += V_bf16 . P'_bf16 via MFMA (r0-verified, stride 72) ------
__global__ __launch_bounds__(256) void pass2(const float* __restrict__ ws,
                                             const u16* __restrict__ vbf,
                                             float* __restrict__ out) {
    __shared__ u16 Pt[64][72];      // P' tile: [m][n]  (B-frag: B[k=n][col=m])
    __shared__ u16 Vt[64][72];      // V tile:  [c][n]  (A-frag: A[row=c][k=n])
    __shared__ float ks[64][8];     // k for this m-tile
    const int t  = threadIdx.x;
    const int b  = blockIdx.z;
    const int m0 = blockIdx.x * 64;
    const int ns = blockIdx.y;
    const float* qkT = ws + OFF_QK + (size_t)b * N * 8;
    const float* ktb = ws + OFF_KT + (size_t)b * N * 8;
    const float* mxv = ws + OFF_MX + (size_t)b * N;
    const float* scv = ws + OFF_SC + (size_t)b * N;
    const u16*   vb  = vbf + (size_t)b * CIN * N;

    if (t < 128) ((float4*)ks)[t] = ((const float4*)(ktb + (size_t)m0 * 8))[t];

    const int lane = t & 63;
    const int wid  = t >> 6;        // wave id -> m-subtile
    const int l16  = lane & 15;
    const int lq   = lane >> 4;     // lane quad -> k-octet / acc row group
    const int vc   = t >> 3;        // V staging row 0..31
    const int vseg = t & 7;

    f32x4 acc[4];
#pragma unroll
    for (int i = 0; i < 4; ++i) acc[i] = (f32x4){0.f, 0.f, 0.f, 0.f};

    for (int ch = 0; ch < 8; ++ch) {
        const int n0 = ns * 512 + ch * 64;
        const int n  = n0 + lane;
        const float4* q4 = (const float4*)(qkT + (size_t)n * 8);
        float4 qa = q4[0], qb = q4[1];
        float mxl = mxv[n], sl = scv[n];
        uint4 v0 = *(const uint4*)(vb + (size_t)vc        * N + n0 + vseg * 8);
        uint4 v1 = *(const uint4*)(vb + (size_t)(vc + 32) * N + n0 + vseg * 8);
        __syncthreads();            // prev chunk's MFMA reads done (chunk 0: ks staged)
#pragma unroll
        for (int r = 0; r < 16; ++r) {
            int mi = wid * 16 + r;
            float4 k0 = *(const float4*)&ks[mi][0];
            float4 k1 = *(const float4*)&ks[mi][4];
            float a = qa.x * k0.x + qa.y * k0.y + qa.z * k0.z + qa.w * k0.w
                    + qb.x * k1.x + qb.y * k1.y + qb.z * k1.z + qb.w * k1.w;
            Pt[mi][lane] = f2bf(__expf(a - mxl) * sl);  // gamma/rowsum folded in
        }
        *(uint4*)&Vt[vc][vseg * 8]      = v0;
        *(uint4*)&Vt[vc + 32][vseg * 8] = v1;
        __syncthreads();
#pragma unroll
        for (int kk = 0; kk < 2; ++kk) {
            int k0i = kk * 32 + lq * 8;
            bf16x8 bfrag = *(const bf16x8*)&Pt[wid * 16 + l16][k0i];
#pragma unroll
            for (int ct = 0; ct < 4; ++ct) {
                bf16x8 afrag = *(const bf16x8*)&Vt[ct * 16 + l16][k0i];
                acc[ct] = __builtin_amdgcn_mfma_f32_16x16x32_bf16(afrag, bfrag, acc[ct], 0, 0, 0);
            }
        }
    }
    float* ob = out + (size_t)b * CIN * N;
    const int mcol = m0 + wid * 16 + l16;
#pragma unroll
    for (int ct = 0; ct < 4; ++ct)
#pragma unroll
        for (int r = 0; r < 4; ++r) {
            int c = ct * 16 + lq * 4 + r;
            atomicAdd(&ob[(size_t)c * N + mcol], acc[ct][r]);
        }
}

extern "C" void kernel_launch(void* const* d_in, const int* in_sizes, int n_in,
                              void* d_out, int out_size, void* d_ws, size_t ws_size,
                              hipStream_t stream) {
    const float* x  = (const float*)d_in[0];
    const float* wq = (const float*)d_in[1];
    const float* bq = (const float*)d_in[2];
    const float* wk = (const float*)d_in[3];
    const float* bk = (const float*)d_in[4];
    const float* wj = (const float*)d_in[5];
    const float* bj = (const float*)d_in[6];
    const float* wv = (const float*)d_in[7];
    const float* bv = (const float*)d_in[8];
    const float* gamma = (const float*)d_in[9];
    float* ws  = (float*)d_ws;
    float* out = (float*)d_out;
    u16* vbf = (u16*)(ws + OFF_V);

    // 3 dispatches (kjqkj absorbed into prep-A + pass1; ~14us/boundary)
    prep<<<dim3(16, 10, 2), 512, 0, stream>>>(x, wq, bq, wk, bk, wj, bj, wv, bv, ws, vbf, out);
    pass1<<<2048, 512, 0, stream>>>(ws, ws, gamma);
    pass2<<<dim3(64, 8, 2), 256, 0, stream>>>(ws, vbf, out);
}

// Round 11
// 145.430 us; speedup vs baseline: 2.9463x; 1.1015x over previous
//
#include <hip/hip_runtime.h>

#define N 4096
#define CIN 64
#define NB 2

typedef unsigned short u16;
typedef short bf16x8 __attribute__((ext_vector_type(8)));
typedef float f32x4 __attribute__((ext_vector_type(4)));

// workspace layout (float offsets). OFF_V region holds bf16 (u16) V.
// OFF_QK holds qkj[n][8] = q[n] . kj ; OFF_KJ holds 64 per-b kj partials (8x8)
#define OFF_QT 0
#define OFF_KT (OFF_QT + NB*N*8)
#define OFF_JT (OFF_KT + NB*N*8)
#define OFF_V  (OFF_JT + NB*N*8)
#define OFF_QK (OFF_V + NB*CIN*N)
#define OFF_MX (OFF_QK + NB*N*8)
#define OFF_SC (OFF_MX + NB*N)
#define OFF_KJ (OFF_SC + NB*N)     // NB*64*64 floats of kj partials

__device__ __forceinline__ u16 f2bf(float f) {
    union { float f; unsigned u; } v; v.f = f;
    unsigned r = (v.u + 0x7fffu + ((v.u >> 16) & 1u)) >> 16;  // RNE
    return (u16)r;
}

// ---- prep v4: flat grid 512, block 512 -------------------------------------
// Per b (256 blocks): r<128 -> V conv (r5-verified); 128<=r<192 -> type A
// (k,j convs, 64 n/block, 8 c-octets across waves); r>=192 -> type B (q conv,
// same shape). Fixes r10's 40.5us prep: A/B had 64 fat blocks (1 wave/SIMD
// tail, occupancy 6.7%); now 256 slim blocks, per-thread 1 octet (40 loads
// in flight), kj reduce on wave 0 only.
__global__ __launch_bounds__(512, 4) void prep(
        const float* __restrict__ x,
        const float* __restrict__ wq, const float* __restrict__ bq,
        const float* __restrict__ wk, const float* __restrict__ bk,
        const float* __restrict__ wj, const float* __restrict__ bj,
        const float* __restrict__ wv, const float* __restrict__ bv,
        float* __restrict__ ws, u16* __restrict__ vbf, float* __restrict__ out) {
    __shared__ union {
        float ab[2][8][8][64];     // A: [k|j][cq][oct][n]  (16 KB); B uses [0]
        float accv[256][8];        // V half-combine (8 KB)
    } sh;
    const int t   = threadIdx.x;
    const int blk = blockIdx.x;
    const int b   = blk >> 8;
    const int r   = blk & 255;

    if (r < 128) {
        // -------- V conv + out=x copy (r5-verified body) --------------------
        const int tn   = t & 255;
        const int half = t >> 8;
        const int yy   = r >> 4;
        const int bx   = r & 15;
        const int n    = bx * 256 + tn;
        const float* xb = x + (size_t)b * CIN * N + n;
        const int c0base = half * 32;
        int co0 = yy * 8;
        float acc[8];
#pragma unroll
        for (int i = 0; i < 8; ++i) acc[i] = half ? 0.f : bv[co0 + i];
        for (int c0i = 0; c0i < 32; c0i += 8) {
            const int c0 = c0base + c0i;
            float xv[8];
#pragma unroll
            for (int u = 0; u < 8; ++u) xv[u] = xb[(size_t)(c0 + u) * N];
#pragma unroll
            for (int u = 0; u < 8; ++u)
#pragma unroll
                for (int i = 0; i < 8; ++i)
                    acc[i] += wv[(co0 + i) * CIN + c0 + u] * xv[u];
            if ((c0 >> 3) == yy) {               // owning half copies out = x
#pragma unroll
                for (int u = 0; u < 8; ++u)
                    out[(size_t)(b * CIN + c0 + u) * N + n] = xv[u];
            }
        }
        if (half) {
#pragma unroll
            for (int i = 0; i < 8; ++i) sh.accv[tn][i] = acc[i];
        }
        __syncthreads();
        if (!half) {
#pragma unroll
            for (int i = 0; i < 8; ++i)
                vbf[(size_t)(b * CIN + co0 + i) * N + n] = f2bf(acc[i] + sh.accv[tn][i]);
        }
    } else if (r < 192) {
        // -------- type A: k (h-stencil) + j (d-stencil), all 8 cq -----------
        const int bx  = r - 128;           // 0..63
        const int tn  = t & 63;            // n within block; wave w == oct w
        const int oct = t >> 6;            // c-octet 0..7
        const int n   = bx * 64 + tn;
        const float* xb = x + (size_t)b * CIN * N + n;
        const int c0 = oct * 8;
        int d = n & 15, h = n >> 8;
        int ohl = (h > 0) ? -256 : 0, ohh = (h < 15) ? 256 : 0;
        int odl = (d > 0) ? -1 : 0,   odh = (d < 15) ? 1 : 0;
        float mhl = (h > 0) ? 1.f : 0.f, mhh = (h < 15) ? 1.f : 0.f;
        float mdl = (d > 0) ? 1.f : 0.f, mdh = (d < 15) ? 1.f : 0.f;

        float xc[8], xhl[8], xhh[8], xdl[8], xdh[8];     // 40 loads in flight
#pragma unroll
        for (int u = 0; u < 8; ++u) {
            const float* p = xb + (size_t)(c0 + u) * N;
            xc[u]  = p[0];
            xhl[u] = p[ohl]; xhh[u] = p[ohh];
            xdl[u] = p[odl]; xdh[u] = p[odh];
        }
#pragma unroll
        for (int u = 0; u < 8; ++u) {
            xhl[u] *= mhl; xhh[u] *= mhh;
            xdl[u] *= mdl; xdh[u] *= mdh;
        }
        float k[8], j[8];
#pragma unroll
        for (int cq = 0; cq < 8; ++cq) {   // weight rows wave-uniform (SGPR)
            const float4* wk4 = (const float4*)(wk + (cq * CIN + c0) * 3);
            float4 a4 = wk4[0], b4 = wk4[1], c4 = wk4[2],
                   d4 = wk4[3], e4 = wk4[4], f4 = wk4[5];
            k[cq] = a4.x * xhl[0] + a4.y * xc[0] + a4.z * xhh[0]
                  + a4.w * xhl[1] + b4.x * xc[1] + b4.y * xhh[1]
                  + b4.z * xhl[2] + b4.w * xc[2] + c4.x * xhh[2]
                  + c4.y * xhl[3] + c4.z * xc[3] + c4.w * xhh[3]
                  + d4.x * xhl[4] + d4.y * xc[4] + d4.z * xhh[4]
                  + d4.w * xhl[5] + e4.x * xc[5] + e4.y * xhh[5]
                  + e4.z * xhl[6] + e4.w * xc[6] + f4.x * xhh[6]
                  + f4.y * xhl[7] + f4.z * xc[7] + f4.w * xhh[7];
            const float4* wj4 = (const float4*)(wj + (cq * CIN + c0) * 3);
            float4 g4 = wj4[0], h4 = wj4[1], i4 = wj4[2],
                   l4 = wj4[3], m4 = wj4[4], o4 = wj4[5];
            j[cq] = g4.x * xdl[0] + g4.y * xc[0] + g4.z * xdh[0]
                  + g4.w * xdl[1] + h4.x * xc[1] + h4.y * xdh[1]
                  + h4.z * xdl[2] + h4.w * xc[2] + i4.x * xdh[2]
                  + i4.y * xdl[3] + i4.z * xc[3] + i4.w * xdh[3]
                  + l4.x * xdl[4] + l4.y * xc[4] + l4.z * xdh[4]
                  + l4.w * xdl[5] + m4.x * xc[5] + m4.y * xdh[5]
                  + m4.z * xdl[6] + m4.w * xc[6] + o4.x * xdh[6]
                  + o4.y * xdl[7] + o4.z * xc[7] + o4.w * xdh[7];
        }
#pragma unroll
        for (int cq = 0; cq < 8; ++cq) {
            sh.ab[0][cq][oct][tn] = k[cq];
            sh.ab[1][cq][oct][tn] = j[cq];
        }
        __syncthreads();
        if (oct == 0) {                    // wave 0 finishes 64 n
#pragma unroll
            for (int cq = 0; cq < 8; ++cq) {
                float ks2 = bk[cq], js2 = bj[cq];
#pragma unroll
                for (int o = 0; o < 8; ++o) {
                    ks2 += sh.ab[0][cq][o][tn];
                    js2 += sh.ab[1][cq][o][tn];
                }
                k[cq] = ks2; j[cq] = js2;
            }
            size_t base = (size_t)(b * N + n) * 8;
#pragma unroll
            for (int cq = 0; cq < 8; ++cq) {
                ws[OFF_KT + base + cq] = k[cq];
                ws[OFF_JT + base + cq] = j[cq];
            }
            // kj partial over this block's 64 n (r9-verified reduce, 1 wave)
#pragma unroll
            for (int g = 0; g < 4; ++g) {
                float a16[16];
#pragma unroll
                for (int cc = 0; cc < 2; ++cc)
#pragma unroll
                    for (int dd = 0; dd < 8; ++dd)
                        a16[cc * 8 + dd] = k[g * 2 + cc] * j[dd];
#pragma unroll
                for (int s = 32; s >= 1; s >>= 1)
#pragma unroll
                    for (int i = 0; i < 16; ++i) a16[i] += __shfl_down(a16[i], s, 64);
                if (tn == 0) {
#pragma unroll
                    for (int i = 0; i < 16; ++i)
                        ws[OFF_KJ + (size_t)(b * 64 + bx) * 64 + g * 16 + i] = a16[i];
                }
            }
        }
    } else {
        // -------- type B: q (w-stencil), all 8 cq ---------------------------
        const int bx  = r - 192;
        const int tn  = t & 63;
        const int oct = t >> 6;
        const int n   = bx * 64 + tn;
        const float* xb = x + (size_t)b * CIN * N + n;
        const int c0 = oct * 8;
        int w = (n >> 4) & 15;
        int owl = (w > 0) ? -16 : 0, owh = (w < 15) ? 16 : 0;
        float mwl = (w > 0) ? 1.f : 0.f, mwh = (w < 15) ? 1.f : 0.f;

        float xc[8], xwl[8], xwh[8];
#pragma unroll
        for (int u = 0; u < 8; ++u) {
            const float* p = xb + (size_t)(c0 + u) * N;
            xc[u] = p[0]; xwl[u] = p[owl]; xwh[u] = p[owh];
        }
#pragma unroll
        for (int u = 0; u < 8; ++u) { xwl[u] *= mwl; xwh[u] *= mwh; }
        float q[8];
#pragma unroll
        for (int cq = 0; cq < 8; ++cq) {
            const float4* w4 = (const float4*)(wq + (cq * CIN + c0) * 3);
            float4 a4 = w4[0], b4 = w4[1], c4 = w4[2],
                   d4 = w4[3], e4 = w4[4], f4 = w4[5];
            q[cq] = a4.x * xwl[0] + a4.y * xc[0] + a4.z * xwh[0]
                  + a4.w * xwl[1] + b4.x * xc[1] + b4.y * xwh[1]
                  + b4.z * xwl[2] + b4.w * xc[2] + c4.x * xwh[2]
                  + c4.y * xwl[3] + c4.z * xc[3] + c4.w * xwh[3]
                  + d4.x * xwl[4] + d4.y * xc[4] + d4.z * xwh[4]
                  + d4.w * xwl[5] + e4.x * xc[5] + e4.y * xwh[5]
                  + e4.z * xwl[6] + e4.w * xc[6] + f4.x * xwh[6]
                  + f4.y * xwl[7] + f4.z * xc[7] + f4.w * xwh[7];
        }
#pragma unroll
        for (int cq = 0; cq < 8; ++cq) sh.ab[0][cq][oct][tn] = q[cq];
        __syncthreads();
        if (oct == 0) {
            size_t base = (size_t)(b * N + n) * 8;
#pragma unroll
            for (int cq = 0; cq < 8; ++cq) {
                float qs = bq[cq];
#pragma unroll
                for (int o = 0; o < 8; ++o) qs += sh.ab[0][cq][o][tn];
                ws[OFF_QT + base + cq] = qs;
            }
        }
    }
}

// ---- pass1: kj from 64 partials + qkj + two-phase softmax stats ------------
__global__ __launch_bounds__(512, 4) void pass1(const float* __restrict__ ws_in,
                                                float* __restrict__ ws,
                                                const float* __restrict__ gamma) {
    __shared__ float kj8[8][64];
    __shared__ float kjs[64];
    __shared__ float smx[8][4];     // [m-eighth wave][row]
    __shared__ float ssum[8][4];
    const int t = threadIdx.x, lane = t & 63, wid = t >> 6;
    const int r0 = blockIdx.x * 4;  // global row base (b*N+n)
    const int b  = r0 >> 12;
    const float* ktb = ws_in + OFF_KT + (size_t)b * N * 8;

    // kj = sum of 64 per-bx partials (16KB, L2-hot); two-level sum
    {
        const int p8 = t >> 6, e = t & 63;
        const float* kjw = ws_in + OFF_KJ + (size_t)b * 64 * 64;
        float s = 0.f;
#pragma unroll
        for (int i = 0; i < 8; ++i) s += kjw[(p8 * 8 + i) * 64 + e];
        kj8[p8][e] = s;
    }
    __syncthreads();
    if (t < 64) {
        float s = 0.f;
#pragma unroll
        for (int p = 0; p < 8; ++p) s += kj8[p][t];
        kjs[t] = s;
    }
    __syncthreads();

    // qkj for this block's 4 rows (every thread; kj read from LDS broadcast)
    float4 qa[4], qb[4];
#pragma unroll
    for (int rr = 0; rr < 4; ++rr) {
        const float4* q4 = (const float4*)(ws_in + OFF_QT + (size_t)(r0 + rr) * 8);
        float4 a4 = q4[0], b4 = q4[1];
        float qv[8] = {a4.x, a4.y, a4.z, a4.w, b4.x, b4.y, b4.z, b4.w};
        float o[8];
#pragma unroll
        for (int dd = 0; dd < 8; ++dd) {
            float a = 0.f;
#pragma unroll
            for (int c = 0; c < 8; ++c) a += qv[c] * kjs[c * 8 + dd];
            o[dd] = a;
        }
        qa[rr] = make_float4(o[0], o[1], o[2], o[3]);
        qb[rr] = make_float4(o[4], o[5], o[6], o[7]);
    }
    // publish qkj rows for pass2 (wave 0, lanes 0..31)
    if (wid == 0 && lane < 32) {
        const int rr = lane >> 3, dd = lane & 7;
        const float* qr = ws_in + OFF_QT + (size_t)(r0 + rr) * 8;
        float o = 0.f;
#pragma unroll
        for (int c = 0; c < 8; ++c) o += qr[c] * kjs[c * 8 + dd];
        ws[OFF_QK + (size_t)r0 * 8 + lane] = o;   // == (r0+rr)*8 + dd
    }

    float as[4][8];                 // scores in registers (32 VGPRs, no spill)
#pragma unroll
    for (int i = 0; i < 8; ++i) {
        const int m = wid * 512 + i * 64 + lane;
        const float4* kk4 = (const float4*)(ktb + (size_t)m * 8);
        float4 ka = kk4[0], kb2 = kk4[1];
#pragma unroll
        for (int rr = 0; rr < 4; ++rr)
            as[rr][i] = qa[rr].x * ka.x + qa[rr].y * ka.y + qa[rr].z * ka.z + qa[rr].w * ka.w
                      + qb[rr].x * kb2.x + qb[rr].y * kb2.y + qb[rr].z * kb2.z + qb[rr].w * kb2.w;
    }

    float mx[4];
#pragma unroll
    for (int rr = 0; rr < 4; ++rr) {
        float m01 = fmaxf(fmaxf(as[rr][0], as[rr][1]), fmaxf(as[rr][2], as[rr][3]));
        float m23 = fmaxf(fmaxf(as[rr][4], as[rr][5]), fmaxf(as[rr][6], as[rr][7]));
        mx[rr] = fmaxf(m01, m23);
    }
#pragma unroll
    for (int s = 32; s >= 1; s >>= 1)
#pragma unroll
        for (int rr = 0; rr < 4; ++rr)
            mx[rr] = fmaxf(mx[rr], __shfl_xor(mx[rr], s, 64));
    if (lane == 0) {
#pragma unroll
        for (int rr = 0; rr < 4; ++rr) smx[wid][rr] = mx[rr];
    }
    __syncthreads();
    float gm[4];
#pragma unroll
    for (int rr = 0; rr < 4; ++rr) {
        float g0 = fmaxf(fmaxf(smx[0][rr], smx[1][rr]), fmaxf(smx[2][rr], smx[3][rr]));
        float g1 = fmaxf(fmaxf(smx[4][rr], smx[5][rr]), fmaxf(smx[6][rr], smx[7][rr]));
        gm[rr] = fmaxf(g0, g1);
    }

    float sm[4];
#pragma unroll
    for (int rr = 0; rr < 4; ++rr) {
        float s0 = __expf(as[rr][0] - gm[rr]) + __expf(as[rr][1] - gm[rr])
                 + __expf(as[rr][2] - gm[rr]) + __expf(as[rr][3] - gm[rr]);
        float s1 = __expf(as[rr][4] - gm[rr]) + __expf(as[rr][5] - gm[rr])
                 + __expf(as[rr][6] - gm[rr]) + __expf(as[rr][7] - gm[rr]);
        sm[rr] = s0 + s1;
    }
#pragma unroll
    for (int s = 32; s >= 1; s >>= 1)
#pragma unroll
        for (int rr = 0; rr < 4; ++rr)
            sm[rr] += __shfl_xor(sm[rr], s, 64);
    if (lane == 0) {
#pragma unroll
        for (int rr = 0; rr < 4; ++rr) ssum[wid][rr] = sm[rr];
    }
    __syncthreads();
    if (t < 4) {
        float g0 = fmaxf(fmaxf(smx[0][t], smx[1][t]), fmaxf(smx[2][t], smx[3][t]));
        float g1 = fmaxf(fmaxf(smx[4][t], smx[5][t]), fmaxf(smx[6][t], smx[7][t]));
        float g  = fmaxf(g0, g1);
        float tt = ((ssum[0][t] + ssum[1][t]) + (ssum[2][t] + ssum[3][t]))
                 + ((ssum[4][t] + ssum[5][t]) + (ssum[6][t] + ssum[7][t]));
        ws[OFF_MX + r0 + t] = g;
        ws[OFF_SC + r0 + t] = gamma[0] / tt;
    }
}

// ---- pass2: out += V_bf16 . P'_bf16 via MFMA (r0-verified, stride 72) ------
__global__ __launch_bounds__(256) void pass2(const float* __restrict__ ws,
                                             const u16* __restrict__ vbf,
                                             float* __restrict__ out) {
    __shared__ u16 Pt[64][72];      // P' tile: [m][n]  (B-frag: B[k=n][col=m])
    __shared__ u16 Vt[64][72];      // V tile:  [c][n]  (A-frag: A[row=c][k=n])
    __shared__ float ks[64][8];     // k for this m-tile
    const int t  = threadIdx.x;
    const int b  = blockIdx.z;
    const int m0 = blockIdx.x * 64;
    const int ns = blockIdx.y;
    const float* qkT = ws + OFF_QK + (size_t)b * N * 8;
    const float* ktb = ws + OFF_KT + (size_t)b * N * 8;
    const float* mxv = ws + OFF_MX + (size_t)b * N;
    const float* scv = ws + OFF_SC + (size_t)b * N;
    const u16*   vb  = vbf + (size_t)b * CIN * N;

    if (t < 128) ((float4*)ks)[t] = ((const float4*)(ktb + (size_t)m0 * 8))[t];

    const int lane = t & 63;
    const int wid  = t >> 6;        // wave id -> m-subtile
    const int l16  = lane & 15;
    const int lq   = lane >> 4;     // lane quad -> k-octet / acc row group
    const int vc   = t >> 3;        // V staging row 0..31
    const int vseg = t & 7;

    f32x4 acc[4];
#pragma unroll
    for (int i = 0; i < 4; ++i) acc[i] = (f32x4){0.f, 0.f, 0.f, 0.f};

    for (int ch = 0; ch < 8; ++ch) {
        const int n0 = ns * 512 + ch * 64;
        const int n  = n0 + lane;
        const float4* q4 = (const float4*)(qkT + (size_t)n * 8);
        float4 qa = q4[0], qb = q4[1];
        float mxl = mxv[n], sl = scv[n];
        uint4 v0 = *(const uint4*)(vb + (size_t)vc        * N + n0 + vseg * 8);
        uint4 v1 = *(const uint4*)(vb + (size_t)(vc + 32) * N + n0 + vseg * 8);
        __syncthreads();            // prev chunk's MFMA reads done (chunk 0: ks staged)
#pragma unroll
        for (int r = 0; r < 16; ++r) {
            int mi = wid * 16 + r;
            float4 k0 = *(const float4*)&ks[mi][0];
            float4 k1 = *(const float4*)&ks[mi][4];
            float a = qa.x * k0.x + qa.y * k0.y + qa.z * k0.z + qa.w * k0.w
                    + qb.x * k1.x + qb.y * k1.y + qb.z * k1.z + qb.w * k1.w;
            Pt[mi][lane] = f2bf(__expf(a - mxl) * sl);  // gamma/rowsum folded in
        }
        *(uint4*)&Vt[vc][vseg * 8]      = v0;
        *(uint4*)&Vt[vc + 32][vseg * 8] = v1;
        __syncthreads();
#pragma unroll
        for (int kk = 0; kk < 2; ++kk) {
            int k0i = kk * 32 + lq * 8;
            bf16x8 bfrag = *(const bf16x8*)&Pt[wid * 16 + l16][k0i];
#pragma unroll
            for (int ct = 0; ct < 4; ++ct) {
                bf16x8 afrag = *(const bf16x8*)&Vt[ct * 16 + l16][k0i];
                acc[ct] = __builtin_amdgcn_mfma_f32_16x16x32_bf16(afrag, bfrag, acc[ct], 0, 0, 0);
            }
        }
    }
    float* ob = out + (size_t)b * CIN * N;
    const int mcol = m0 + wid * 16 + l16;
#pragma unroll
    for (int ct = 0; ct < 4; ++ct)
#pragma unroll
        for (int r = 0; r < 4; ++r) {
            int c = ct * 16 + lq * 4 + r;
            atomicAdd(&ob[(size_t)c * N + mcol], acc[ct][r]);
        }
}

extern "C" void kernel_launch(void* const* d_in, const int* in_sizes, int n_in,
                              void* d_out, int out_size, void* d_ws, size_t ws_size,
                              hipStream_t stream) {
    const float* x  = (const float*)d_in[0];
    const float* wq = (const float*)d_in[1];
    const float* bq = (const float*)d_in[2];
    const float* wk = (const float*)d_in[3];
    const float* bk = (const float*)d_in[4];
    const float* wj = (const float*)d_in[5];
    const float* bj = (const float*)d_in[6];
    const float* wv = (const float*)d_in[7];
    const float* bv = (const float*)d_in[8];
    const float* gamma = (const float*)d_in[9];
    float* ws  = (float*)d_ws;
    float* out = (float*)d_out;
    u16* vbf = (u16*)(ws + OFF_V);

    // 3 dispatches (~16.5us/boundary measured r2/r5/r9/r10 regression)
    prep<<<dim3(512), 512, 0, stream>>>(x, wq, bq, wk, bk, wj, bj, wv, bv, ws, vbf, out);
    pass1<<<2048, 512, 0, stream>>>(ws, ws, gamma);
    pass2<<<dim3(64, 8, 2), 256, 0, stream>>>(ws, vbf, out);
}